// Round 1
// baseline (5150.299 us; speedup 1.0000x reference)
//
#include <hip/hip_runtime.h>
#include <hip/hip_bf16.h>

// Problem: T=16, N=4, Cin=hidden=64, C4=256, H=W=64
#define HW    4096
#define NIMG  64     // T*N
#define NB    4      // N
#define CIN   64
#define C4    256
#define BN_N  262144.0f   // 64*4096 values per channel

__device__ __forceinline__ float bf2f(unsigned short u) {
    union { unsigned ui; float f; } c; c.ui = ((unsigned)u) << 16; return c.f;
}
__device__ __forceinline__ float sigmoidf_(float x) { return 1.0f / (1.0f + expf(-x)); }

// ---------------------------------------------------------------------------
// Kernel 1: conv_x2h (stride1 pad1 3x3), 64 imgs, 64->256 ch, +bias, store bf16
// grid: 64 img * 16 tiles(16x16) * 16 cout-groups(16 co) = 16384 blocks, 256 thr
// ---------------------------------------------------------------------------
__global__ __launch_bounds__(256) void k_conv_x2h(
    const float* __restrict__ x, const float* __restrict__ Wx,
    const float* __restrict__ bx, __hip_bfloat16* __restrict__ y)
{
    __shared__ float patch[32][324];   // 32 cin x 18x18, 41.5 KB

    const int bid  = blockIdx.x;
    const int cg   = bid & 15;            // cout group (16 couts)
    const int tile = (bid >> 4) & 15;
    const int img  = bid >> 8;            // 0..63
    const int ty = tile >> 2, tx = tile & 3;
    const int y0 = ty * 16, x0 = tx * 16;
    const int tid = threadIdx.x;
    const int py = tid >> 4, px = tid & 15;

    float acc[16];
#pragma unroll
    for (int i = 0; i < 16; ++i) acc[i] = 0.f;

    const float* wbase = Wx + (size_t)(cg * 16) * 576;   // [co][ci][9]

    for (int ch = 0; ch < 2; ++ch) {
        __syncthreads();
        // stage 32 cin x 18x18 patch (zero-padded)
        for (int f = tid; f < 32 * 324; f += 256) {
            int ci = f / 324;
            int r  = f - ci * 324;
            int pr = r / 18, pc = r - pr * 18;
            int gy = y0 + pr - 1, gx = x0 + pc - 1;
            float v = 0.f;
            if ((unsigned)gy < 64u && (unsigned)gx < 64u)
                v = x[(((size_t)img * CIN + ch * 32 + ci) * 64 + gy) * 64 + gx];
            patch[ci][r] = v;
        }
        __syncthreads();

        for (int ci = 0; ci < 32; ++ci) {
            float p[9];
#pragma unroll
            for (int ky = 0; ky < 3; ++ky)
#pragma unroll
                for (int kx = 0; kx < 3; ++kx)
                    p[ky * 3 + kx] = patch[ci][(py + ky) * 18 + px + kx];
            const float* w = wbase + (ch * 32 + ci) * 9;   // wave-uniform -> s_load
#pragma unroll
            for (int co = 0; co < 16; ++co) {
#pragma unroll
                for (int k = 0; k < 9; ++k)
                    acc[co] = fmaf(w[co * 576 + k], p[k], acc[co]);
            }
        }
    }

    const int pix = (y0 + py) * 64 + (x0 + px);
#pragma unroll
    for (int co = 0; co < 16; ++co) {
        int c = cg * 16 + co;
        float v = acc[co] + bx[c];
        y[((size_t)img * C4 + c) * HW + pix] = __float2bfloat16(v);
    }
}

// ---------------------------------------------------------------------------
// Kernel 2: BN stats per channel over [64 imgs x 4096 pix] -> scale/shift
// grid: 256 blocks (one per channel), 256 threads
// ---------------------------------------------------------------------------
__global__ __launch_bounds__(256) void k_bn_stats(
    const __hip_bfloat16* __restrict__ y, const float* __restrict__ gamma,
    const float* __restrict__ beta, float* __restrict__ ss)
{
    const int c = blockIdx.x;
    const int tid = threadIdx.x;
    float s = 0.f, sq = 0.f;
    for (int img = 0; img < NIMG; ++img) {
        const ushort4* p4 = reinterpret_cast<const ushort4*>(
            y + ((size_t)img * C4 + c) * HW);
        for (int i = tid; i < HW / 4; i += 256) {
            ushort4 q = p4[i];
            float v0 = bf2f(q.x), v1 = bf2f(q.y), v2 = bf2f(q.z), v3 = bf2f(q.w);
            s  += v0 + v1 + v2 + v3;
            sq += v0 * v0 + v1 * v1 + v2 * v2 + v3 * v3;
        }
    }
    __shared__ float rs[256], rq[256];
    rs[tid] = s; rq[tid] = sq;
    __syncthreads();
    for (int off = 128; off > 0; off >>= 1) {
        if (tid < off) { rs[tid] += rs[tid + off]; rq[tid] += rq[tid + off]; }
        __syncthreads();
    }
    if (tid == 0) {
        float inv  = 1.0f / BN_N;
        float mean = rs[0] * inv;
        float var  = rq[0] * inv - mean * mean;
        float sc   = gamma[c] * rsqrtf(var + 1e-5f);
        ss[c]       = sc;
        ss[C4 + c]  = beta[c] - mean * sc;
    }
}

// ---------------------------------------------------------------------------
// Kernel 3: one LSTM step: tmp = conv(h_prev, Wh) + BN(y[t]); gates; c,h update
// grid: 4 img * 16 tiles * 16 hidden-groups(4 hc x 4 gates) = 1024 blocks
// ---------------------------------------------------------------------------
__global__ __launch_bounds__(256) void k_step(
    const unsigned short* __restrict__ hprev,   // bf16 bits [4][64][4096]
    const float* __restrict__ Wh,
    const __hip_bfloat16* __restrict__ y,
    const float* __restrict__ ss,
    float* __restrict__ c_state,                // [4][64][4096]
    __hip_bfloat16* __restrict__ hnext,
    float* __restrict__ out,                    // [16][4][64][4096]
    int t)
{
    __shared__ float patch[32][324];

    const int bid  = blockIdx.x;
    const int hg   = bid & 15;             // 4 hidden channels per group
    const int tile = (bid >> 4) & 15;
    const int img  = bid >> 8;             // n in 0..3
    const int ty = tile >> 2, tx = tile & 3;
    const int y0 = ty * 16, x0 = tx * 16;
    const int tid = threadIdx.x;
    const int py = tid >> 4, px = tid & 15;

    float acc[16];                          // [gate 4][j 4]
#pragma unroll
    for (int i = 0; i < 16; ++i) acc[i] = 0.f;

    for (int ch = 0; ch < 2; ++ch) {
        __syncthreads();
        for (int f = tid; f < 32 * 324; f += 256) {
            int ci = f / 324;
            int r  = f - ci * 324;
            int pr = r / 18, pc = r - pr * 18;
            int gy = y0 + pr - 1, gx = x0 + pc - 1;
            float v = 0.f;
            if ((unsigned)gy < 64u && (unsigned)gx < 64u)
                v = bf2f(hprev[((size_t)img * CIN + ch * 32 + ci) * HW + gy * 64 + gx]);
            patch[ci][r] = v;
        }
        __syncthreads();

        for (int ci = 0; ci < 32; ++ci) {
            float p[9];
#pragma unroll
            for (int ky = 0; ky < 3; ++ky)
#pragma unroll
                for (int kx = 0; kx < 3; ++kx)
                    p[ky * 3 + kx] = patch[ci][(py + ky) * 18 + px + kx];
#pragma unroll
            for (int u = 0; u < 16; ++u) {
                int co = (u >> 2) * 64 + hg * 4 + (u & 3);
                const float* w = Wh + (size_t)co * 576 + (ch * 32 + ci) * 9; // uniform
#pragma unroll
                for (int k = 0; k < 9; ++k)
                    acc[u] = fmaf(w[k], p[k], acc[u]);
            }
        }
    }

    const int pix  = (y0 + py) * 64 + (x0 + px);
    const int yimg = t * NB + img;
    float tmp[16];
#pragma unroll
    for (int u = 0; u < 16; ++u) {
        int co = (u >> 2) * 64 + hg * 4 + (u & 3);
        float yv = bf2f(reinterpret_cast<const unsigned short*>(y)
                            [((size_t)yimg * C4 + co) * HW + pix]);
        tmp[u] = acc[u] + ss[co] * yv + ss[C4 + co];
    }

#pragma unroll
    for (int j = 0; j < 4; ++j) {
        int hc = hg * 4 + j;
        float iv = sigmoidf_(tmp[0 * 4 + j]);
        float fv = sigmoidf_(tmp[1 * 4 + j]);
        float ov = sigmoidf_(tmp[2 * 4 + j]);
        float gv = tanhf(tmp[3 * 4 + j]);
        size_t idx = ((size_t)img * CIN + hc) * HW + pix;
        float cold = c_state[idx];
        float cnew = fv * cold + iv * gv;
        c_state[idx] = cnew;
        float hv = ov * tanhf(cnew);
        hnext[idx] = __float2bfloat16(hv);
        out[(size_t)t * (NB * CIN * HW) + idx] = hv;
    }
}

// ---------------------------------------------------------------------------
extern "C" void kernel_launch(void* const* d_in, const int* in_sizes, int n_in,
                              void* d_out, int out_size, void* d_ws, size_t ws_size,
                              hipStream_t stream) {
    const float* x     = (const float*)d_in[0];
    const float* Wx    = (const float*)d_in[1];
    const float* bx    = (const float*)d_in[2];
    const float* gamma = (const float*)d_in[3];
    const float* beta  = (const float*)d_in[4];
    const float* Wh    = (const float*)d_in[5];
    float* out = (float*)d_out;

    char* ws = (char*)d_ws;
    // workspace layout
    __hip_bfloat16* y  = (__hip_bfloat16*)ws;                    // 134,217,728 B
    float*          ss = (float*)(ws + 134217728);               // 2,048 B
    float*          cs = (float*)(ws + 134219776);               // 4,194,304 B
    __hip_bfloat16* hA = (__hip_bfloat16*)(ws + 138414080);      // 2,097,152 B
    __hip_bfloat16* hB = (__hip_bfloat16*)(ws + 140511232);      // 2,097,152 B
    // total: 142,608,384 B

    hipMemsetAsync(cs, 0, 4194304, stream);
    hipMemsetAsync(hA, 0, 2097152, stream);

    k_conv_x2h<<<16384, 256, 0, stream>>>(x, Wx, bx, y);
    k_bn_stats<<<256, 256, 0, stream>>>(y, gamma, beta, ss);

    for (int t = 0; t < 16; ++t) {
        __hip_bfloat16* hp = (t & 1) ? hB : hA;
        __hip_bfloat16* hn = (t & 1) ? hA : hB;
        k_step<<<1024, 256, 0, stream>>>(
            reinterpret_cast<const unsigned short*>(hp), Wh, y, ss, cs, hn, out, t);
    }
}

// Round 4
// 470.938 us; speedup vs baseline: 10.9363x; 10.9363x over previous
//
#include <hip/hip_runtime.h>
#include <hip/hip_bf16.h>

// T=16, N=4, Cin=hidden=64, C4=256, H=W=64
typedef float        f32x4  __attribute__((ext_vector_type(4)));
typedef unsigned int u32x4  __attribute__((ext_vector_type(4)));
typedef __bf16       bf16x8 __attribute__((ext_vector_type(8)));

__device__ __forceinline__ unsigned short f2bf(float f) {
    unsigned u = __builtin_bit_cast(unsigned, f);
    u += 0x7fffu + ((u >> 16) & 1u);          // RTN-even (finite inputs)
    return (unsigned short)(u >> 16);
}
__device__ __forceinline__ float bf2f(unsigned short u) {
    union { unsigned ui; float f; } c; c.ui = ((unsigned)u) << 16; return c.f;
}

// ---------------------------------------------------------------------------
// xT: [img][pix][ci] bf16  <-  x [img][ci][pix] f32
// ---------------------------------------------------------------------------
__global__ __launch_bounds__(256) void k_xT(const float* __restrict__ x,
                                            unsigned short* __restrict__ xT) {
    int bid = blockIdx.x;                // 1024
    int img = bid >> 4;
    int p   = (bid & 15) * 256 + threadIdx.x;
    const float* xi = x + (size_t)img * 64 * 4096 + p;
    unsigned short r[64];
#pragma unroll
    for (int ci = 0; ci < 64; ++ci) r[ci] = f2bf(xi[(size_t)ci * 4096]);
    u32x4* dst = (u32x4*)(xT + ((size_t)img * 4096 + p) * 64);
#pragma unroll
    for (int c8 = 0; c8 < 8; ++c8) dst[c8] = *(u32x4*)&r[c8 * 8];
}

// ---------------------------------------------------------------------------
// Pack weights [256][64][3][3] f32 -> A bf16 [row][tap*64+ci], chunk-preswizzled
// gatePerm: row = hc*4+g  ->  orig co = g*64+hc   (for Wh)
// ---------------------------------------------------------------------------
__global__ __launch_bounds__(256) void k_pack(const float* __restrict__ W,
                                              unsigned short* __restrict__ Ap,
                                              int gatePerm) {
    int idx = blockIdx.x * 256 + threadIdx.x;      // 576 blocks
    if (idx >= 256 * 576) return;
    int row = idx / 576, k = idx % 576;
    int tap = k / 64, cil = k % 64;
    int kb = cil >> 5, w32 = cil & 31;
    int s = w32 >> 3, e = w32 & 7;
    int ci = kb * 32 + ((s ^ (row & 3)) << 3) + e;     // pre-swizzle chunks
    int co = gatePerm ? ((row & 3) * 64 + (row >> 2)) : row;
    Ap[idx] = f2bf(W[((size_t)co * 64 + ci) * 9 + tap]);
}

// ---------------------------------------------------------------------------
// Unified MFMA conv core.  MODE 0: x2h (write y bf16).  MODE 1: LSTM step.
// block: 256 thr (4 waves), 16x16 spatial tile, 64 packed A-rows, K=576.
// grid: MODE0: 64img*16tile*4cog=4096.  MODE1: 4img*16tile*4hcg=256.
// ---------------------------------------------------------------------------
template<int MODE>
__global__ __launch_bounds__(256) void k_conv(
    const unsigned short* __restrict__ src,   // [img][4096][64] bf16
    const unsigned short* __restrict__ Ap,    // packed weights
    unsigned short* __restrict__ ybf,         // MODE0: out, MODE1: in
    const float* __restrict__ ss,             // [2][256] scale/shift (MODE1)
    float* __restrict__ cst,                  // [4][64][4096] (MODE1)
    unsigned short* __restrict__ hout,        // [4][4096][64] (MODE1)
    float* __restrict__ out,                  // [16][4][64][4096] (MODE1)
    int t, int first)
{
    __shared__ __align__(16) unsigned short halo[18 * 18 * 64];  // 41472 B
    __shared__ __align__(16) unsigned short As[2][64 * 32];      //  8192 B

    const int bid  = blockIdx.x;
    const int grp  = bid & 3;                 // cog / hcg
    const int tile = (bid >> 2) & 15;
    const int img  = bid >> 6;
    const int py0 = (tile >> 2) * 16, px0 = (tile & 3) * 16;
    const int tid = threadIdx.x;
    const int wv = tid >> 6, lane = tid & 63;
    const int cl = lane & 15, q = lane >> 4;
    const int rowbase = grp * 64;

    f32x4 acc[4][4];
#pragma unroll
    for (int m = 0; m < 4; ++m)
#pragma unroll
        for (int n = 0; n < 4; ++n)
            acc[m][n] = (f32x4){0.f, 0.f, 0.f, 0.f};

    const bool skip = (MODE == 1) && first;

    if (!skip) {
        // ---- halo staging: 18x18 positions x 8 ci-chunks, XOR-swizzled ----
        const unsigned short* sb = src + (size_t)img * 4096 * 64;
        char* hB = (char*)halo;
        for (int tau = tid; tau < 2592; tau += 256) {
            int s = tau & 7, hcc = (tau >> 3) % 18, hrr = tau / 144;
            int gy = py0 + hrr - 1, gx = px0 + hcc - 1;
            u32x4 v = {0u, 0u, 0u, 0u};
            if ((unsigned)gy < 64u && (unsigned)gx < 64u)
                v = *(const u32x4*)(sb + ((gy * 64 + gx) * 64 + s * 8));
            *(u32x4*)(hB + (hrr * 18 + hcc) * 128 + ((s * 16) ^ ((hcc & 7) << 4))) = v;
        }
        // ---- A slab staging: 64 rows x 32 ci per k-step (pre-swizzled src) ----
        const char* agp = (const char*)Ap +
            ((size_t)(rowbase + (tid >> 2)) * 576) * 2 + (tid & 3) * 16;
        char* AsWr = (char*)(&As[0][0]) + (tid >> 2) * 64 + (tid & 3) * 16;
        *(u32x4*)AsWr = *(const u32x4*)agp;       // ks = 0
        __syncthreads();

        // per-m a-frag byte offsets (constant over ks)
        int aoff[4];
#pragma unroll
        for (int m = 0; m < 4; ++m)
            aoff[m] = (m * 16 + cl) * 64 + ((q * 16) ^ ((cl & 3) << 4));

        const char* AsRd = (const char*)(&As[0][0]);
        int buf = 0;
        for (int ks = 0; ks < 18; ++ks) {
            bool have = ks < 17;
            u32x4 an;
            if (have) an = *(const u32x4*)(agp + (ks + 1) * 64);

            int tap = ks >> 1, kb = ks & 1;
            int ky = tap / 3, kx = tap - ky * 3;

            u32x4 af[4];
#pragma unroll
            for (int m = 0; m < 4; ++m)
                af[m] = *(const u32x4*)(AsRd + buf * 4096 + aoff[m]);

            int hcv  = cl + kx;
            int cbase = hcv * 128 + ((kb * 64 + q * 16) ^ ((hcv & 7) << 4));
#pragma unroll
            for (int n = 0; n < 4; ++n) {
                int hr = wv * 4 + n + ky;
                u32x4 bv = *(const u32x4*)(hB + hr * 2304 + cbase);
                bf16x8 bfr = __builtin_bit_cast(bf16x8, bv);
#pragma unroll
                for (int m = 0; m < 4; ++m)
                    acc[m][n] = __builtin_amdgcn_mfma_f32_16x16x32_bf16(
                        __builtin_bit_cast(bf16x8, af[m]), bfr, acc[m][n], 0, 0, 0);
            }
            if (have) *(u32x4*)(AsWr + ((buf ^ 1) << 12)) = an;
            __syncthreads();
            buf ^= 1;
        }
    }

    if (MODE == 0) {
        // ---- y = conv (bias cancels in train-mode BN; never added) ----
#pragma unroll
        for (int m = 0; m < 4; ++m) {
            int co = rowbase + m * 16 + q * 4;
#pragma unroll
            for (int n = 0; n < 4; ++n) {
                int pix = (py0 + wv * 4 + n) * 64 + px0 + cl;
                unsigned short* yp = ybf + (size_t)img * 256 * 4096 + pix;
#pragma unroll
                for (int j = 0; j < 4; ++j)
                    yp[(size_t)(co + j) * 4096] = f2bf(acc[m][n][j]);
            }
        }
    } else {
        unsigned short* hbounce = &As[0][0];     // 8 KB reuse
        __syncthreads();
#pragma unroll
        for (int m = 0; m < 4; ++m) {
            int hc = grp * 16 + m * 4 + q;
            float sc[4], sh[4];
#pragma unroll
            for (int j = 0; j < 4; ++j) {
                sc[j] = ss[j * 64 + hc];
                sh[j] = ss[256 + j * 64 + hc];
            }
#pragma unroll
            for (int n = 0; n < 4; ++n) {
                int pix = (py0 + wv * 4 + n) * 64 + px0 + cl;
                float tmp[4];
#pragma unroll
                for (int j = 0; j < 4; ++j) {
                    float yv = bf2f(ybf[((size_t)((t * 4 + img) * 256 + j * 64 + hc)) * 4096 + pix]);
                    tmp[j] = acc[m][n][j] + sc[j] * yv + sh[j];
                }
                float iv = 1.f / (1.f + __expf(-tmp[0]));
                float fv = 1.f / (1.f + __expf(-tmp[1]));
                float ov = 1.f / (1.f + __expf(-tmp[2]));
                float e2 = __expf(2.f * tmp[3]);
                float gv = 1.f - 2.f / (e2 + 1.f);
                size_t cidx = ((size_t)img * 64 + hc) * 4096 + pix;
                float cnew = fv * cst[cidx] + iv * gv;
                cst[cidx] = cnew;
                float e2c = __expf(2.f * cnew);
                float hv  = ov * (1.f - 2.f / (e2c + 1.f));
                out[((size_t)(t * 4 + img) * 64 + hc) * 4096 + pix] = hv;
                hbounce[((wv * 4 + n) * 16 + cl) * 16 + m * 4 + q] = f2bf(hv);
            }
        }
        __syncthreads();
        // coalesced hT write-out: [img][pix][ci] slice grp*16..grp*16+15
        {
            int lp = tid;
            int pixg = (py0 + (lp >> 4)) * 64 + px0 + (lp & 15);
            u32x4* dst = (u32x4*)(hout + ((size_t)img * 4096 + pixg) * 64 + grp * 16);
            u32x4* s0  = (u32x4*)(hbounce + lp * 16);
            dst[0] = s0[0];
            dst[1] = s0[1];
        }
    }
}

// ---------------------------------------------------------------------------
// BN stats: partial sums per (channel, img-group of 8)
// ---------------------------------------------------------------------------
__global__ __launch_bounds__(256) void k_bn_part(const unsigned short* __restrict__ y,
                                                 float2* __restrict__ part) {
    int co = blockIdx.x >> 3, g = blockIdx.x & 7;
    float s = 0.f, sq = 0.f;
    for (int im = 0; im < 8; ++im) {
        const unsigned short* row = y + ((size_t)((g * 8 + im) * 256 + co)) * 4096;
        for (int i0 = threadIdx.x * 8; i0 < 4096; i0 += 2048) {
            u32x4 v = *(const u32x4*)(row + i0);
#pragma unroll
            for (int e = 0; e < 4; ++e) {
                float a = bf2f((unsigned short)(v[e] & 0xffffu));
                float b = bf2f((unsigned short)(v[e] >> 16));
                s += a + b; sq += a * a + b * b;
            }
        }
    }
    __shared__ float rs[256], rq[256];
    int tid = threadIdx.x;
    rs[tid] = s; rq[tid] = sq;
    __syncthreads();
    for (int off = 128; off > 0; off >>= 1) {
        if (tid < off) { rs[tid] += rs[tid + off]; rq[tid] += rq[tid + off]; }
        __syncthreads();
    }
    if (tid == 0) part[blockIdx.x] = make_float2(rs[0], rq[0]);
}

__global__ void k_bn_fin(const float2* __restrict__ part, const float* __restrict__ bx,
                         const float* __restrict__ gamma, const float* __restrict__ beta,
                         float* __restrict__ ss) {
    int c = threadIdx.x;                      // 256
    float s = 0.f, sq = 0.f;
    for (int g = 0; g < 8; ++g) { float2 p = part[c * 8 + g]; s += p.x; sq += p.y; }
    float mean = s * (1.f / 262144.f);
    float var  = sq * (1.f / 262144.f) - mean * mean;
    float sc   = gamma[c] * rsqrtf(var + 1e-5f);
    ss[c]       = sc;
    // conv bias bx cancels exactly in train-mode BN (mean contains it);
    // y was stored WITHOUT bias, so stats already match the bias-free conv:
    ss[256 + c] = beta[c] - mean * sc;
    (void)bx;
}

// ---------------------------------------------------------------------------
extern "C" void kernel_launch(void* const* d_in, const int* in_sizes, int n_in,
                              void* d_out, int out_size, void* d_ws, size_t ws_size,
                              hipStream_t stream) {
    const float* x     = (const float*)d_in[0];
    const float* Wx    = (const float*)d_in[1];
    const float* bx    = (const float*)d_in[2];
    const float* gamma = (const float*)d_in[3];
    const float* beta  = (const float*)d_in[4];
    const float* Wh    = (const float*)d_in[5];
    float* out = (float*)d_out;

    char* ws = (char*)d_ws;
    unsigned short* y   = (unsigned short*)ws;                  // 134,217,728
    unsigned short* Axp = (unsigned short*)(ws + 134217728);    //     294,912
    unsigned short* Ahp = (unsigned short*)(ws + 134512640);    //     294,912
    float*          ss  = (float*)(ws + 134807552);             //       2,048
    float2*         prt = (float2*)(ws + 134809600);            //      16,384
    float*          cs  = (float*)(ws + 134825984);             //   4,194,304
    unsigned short* hA  = (unsigned short*)(ws + 139020288);    //   2,097,152
    unsigned short* hB  = (unsigned short*)(ws + 141117440);    //   2,097,152
    // total 143,214,592 B

    // xT scratch lives in d_out (dead once steps start overwriting it)
    unsigned short* xT = (unsigned short*)d_out;

    k_xT  <<<1024, 256, 0, stream>>>(x, xT);
    k_pack<<< 576, 256, 0, stream>>>(Wx, Axp, 0);
    k_pack<<< 576, 256, 0, stream>>>(Wh, Ahp, 1);
    hipMemsetAsync(cs, 0, 4194304, stream);

    k_conv<0><<<4096, 256, 0, stream>>>(xT, Axp, y,
                                        nullptr, nullptr, nullptr, nullptr, 0, 0);
    k_bn_part<<<2048, 256, 0, stream>>>(y, prt);
    k_bn_fin <<<   1, 256, 0, stream>>>(prt, bx, gamma, beta, ss);

    unsigned short* hbuf[2] = {hA, hB};
    for (int t = 0; t < 16; ++t) {
        k_conv<1><<<256, 256, 0, stream>>>(hbuf[t & 1], Ahp, y, ss, cs,
                                           hbuf[(t + 1) & 1], out, t, t == 0 ? 1 : 0);
    }
}

// Round 5
// 432.923 us; speedup vs baseline: 11.8966x; 1.0878x over previous
//
#include <hip/hip_runtime.h>
#include <hip/hip_bf16.h>

// T=16, N=4, Cin=hidden=64, C4=256, H=W=64
typedef float        f32x4  __attribute__((ext_vector_type(4)));
typedef unsigned int u32x4  __attribute__((ext_vector_type(4)));
typedef __bf16       bf16x8 __attribute__((ext_vector_type(8)));

__device__ __forceinline__ unsigned short f2bf(float f) {
    unsigned u = __builtin_bit_cast(unsigned, f);
    u += 0x7fffu + ((u >> 16) & 1u);          // RTN-even (finite inputs)
    return (unsigned short)(u >> 16);
}
__device__ __forceinline__ float bf2f(unsigned short u) {
    union { unsigned ui; float f; } c; c.ui = ((unsigned)u) << 16; return c.f;
}

// ---------------------------------------------------------------------------
// xT: [img][pix][ci] bf16  <-  x [img][ci][pix] f32
// ---------------------------------------------------------------------------
__global__ __launch_bounds__(256) void k_xT(const float* __restrict__ x,
                                            unsigned short* __restrict__ xT) {
    int bid = blockIdx.x;                // 1024
    int img = bid >> 4;
    int p   = (bid & 15) * 256 + threadIdx.x;
    const float* xi = x + (size_t)img * 64 * 4096 + p;
    unsigned short r[64];
#pragma unroll
    for (int ci = 0; ci < 64; ++ci) r[ci] = f2bf(xi[(size_t)ci * 4096]);
    u32x4* dst = (u32x4*)(xT + ((size_t)img * 4096 + p) * 64);
#pragma unroll
    for (int c8 = 0; c8 < 8; ++c8) dst[c8] = *(u32x4*)&r[c8 * 8];
}

// ---------------------------------------------------------------------------
// Pack weights [256][64][3][3] f32 -> A bf16 [row][tap*64+ci], chunk-preswizzled
// gatePerm: row = hc*4+g  ->  orig co = g*64+hc   (for Wh)
// ---------------------------------------------------------------------------
__global__ __launch_bounds__(256) void k_pack(const float* __restrict__ W,
                                              unsigned short* __restrict__ Ap,
                                              int gatePerm) {
    int idx = blockIdx.x * 256 + threadIdx.x;      // 576 blocks
    if (idx >= 256 * 576) return;
    int row = idx / 576, k = idx % 576;
    int tap = k / 64, cil = k % 64;
    int kb = cil >> 5, w32 = cil & 31;
    int s = w32 >> 3, e = w32 & 7;
    int ci = kb * 32 + ((s ^ (row & 3)) << 3) + e;     // pre-swizzle chunks
    int co = gatePerm ? ((row & 3) * 64 + (row >> 2)) : row;
    Ap[idx] = f2bf(W[((size_t)co * 64 + ci) * 9 + tap]);
}

// ---------------------------------------------------------------------------
// Unified MFMA conv core.  MODE 0: x2h (write y bf16 + BN partials).
// MODE 1: LSTM step (8x16 tile).  Halo staged 32-ci half at a time.
// MODE0: grid 64img*16tile(16x16)*4cog = 4096 blocks.
// MODE1: grid 4img*32tile(8x16)*4hcg  =  512 blocks.
// ---------------------------------------------------------------------------
template<int MODE>
__global__ __launch_bounds__(256) void k_conv(
    const unsigned short* __restrict__ src,   // [img][4096][64] bf16
    const unsigned short* __restrict__ Ap,    // packed weights
    unsigned short* __restrict__ ybf,         // MODE0: out, MODE1: in
    const float* __restrict__ ss,             // [2][256] scale/shift (MODE1)
    float* __restrict__ cst,                  // [4][64][4096] (MODE1)
    unsigned short* __restrict__ hout,        // [4][4096][64] (MODE1)
    float* __restrict__ out,                  // [16][4][64][4096] (MODE1)
    float2* __restrict__ prt,                 // [256ch][1024] BN partials (MODE0)
    int t, int first)
{
    constexpr int TH    = MODE ? 8 : 16;      // tile rows
    constexpr int N_    = MODE ? 2 : 4;       // pixel-rows per wave
    constexpr int HR    = TH + 2;             // halo rows
    constexpr int TMSK  = MODE ? 31 : 15;
    constexpr int IMGSH = MODE ? 7 : 6;

    __shared__ __align__(16) unsigned short halo[HR * 18 * 32];  // 20736 / 11520 B
    __shared__ __align__(16) unsigned short As[2][64 * 32];      //  8192 B

    const int bid  = blockIdx.x;
    const int grp  = bid & 3;                 // cog / hcg
    const int tile = (bid >> 2) & TMSK;
    const int img  = bid >> IMGSH;
    const int py0 = (tile >> 2) * TH, px0 = (tile & 3) * 16;
    const int tid = threadIdx.x;
    const int wv = tid >> 6, lane = tid & 63;
    const int cl = lane & 15, q = lane >> 4;
    const int rowbase = grp * 64;

    f32x4 acc[4][N_];
#pragma unroll
    for (int m = 0; m < 4; ++m)
#pragma unroll
        for (int n = 0; n < N_; ++n)
            acc[m][n] = (f32x4){0.f, 0.f, 0.f, 0.f};

    const bool skip = (MODE == 1) && first;

    if (!skip) {
        const unsigned short* sb = src + (size_t)img * 4096 * 64;
        char* hB = (char*)halo;
        auto stage_halo = [&](int ch2) {
            for (int tau = tid; tau < HR * 72; tau += 256) {
                int s = tau & 3, hcc = (tau >> 2) % 18, hrr = tau / 72;
                int gy = py0 + hrr - 1, gx = px0 + hcc - 1;
                u32x4 v = {0u, 0u, 0u, 0u};
                if ((unsigned)gy < 64u && (unsigned)gx < 64u)
                    v = *(const u32x4*)(sb + ((gy * 64 + gx) * 64 + ch2 * 32 + s * 8));
                *(u32x4*)(hB + (hrr * 18 + hcc) * 64 + ((s * 16) ^ ((hcc & 3) << 4))) = v;
            }
        };
        // A slab staging: 64 rows x 32 ci per k-step (pre-swizzled src)
        const char* agp = (const char*)Ap +
            (size_t)(rowbase + (tid >> 2)) * 1152 + (tid & 3) * 16;
        char* AsWr = (char*)(&As[0][0]) + (tid >> 2) * 64 + (tid & 3) * 16;
        *(u32x4*)AsWr = *(const u32x4*)agp;       // ks = 0 (tap0, half0)
        stage_halo(0);
        __syncthreads();

        int aoff[4];
#pragma unroll
        for (int m = 0; m < 4; ++m)
            aoff[m] = (m * 16 + cl) * 64 + ((q * 16) ^ ((cl & 3) << 4));

        const char* AsRd = (const char*)(&As[0][0]);
        int buf = 0;
        for (int ks = 0; ks < 18; ++ks) {
            int tap = ks % 9;
            int ky = tap / 3, kx = tap - ky * 3;
            bool have = ks < 17;
            u32x4 an;
            if (have) {
                int ksn = ks + 1, tapn = ksn % 9, ch2n = ksn / 9;
                an = *(const u32x4*)(agp + tapn * 128 + ch2n * 64);
            }
            u32x4 af[4];
#pragma unroll
            for (int m = 0; m < 4; ++m)
                af[m] = *(const u32x4*)(AsRd + buf * 4096 + aoff[m]);

            int hcv  = cl + kx;
            int cbase = hcv * 64 + ((q * 16) ^ ((hcv & 3) << 4));
#pragma unroll
            for (int n = 0; n < N_; ++n) {
                int hr = wv * N_ + n + ky;
                u32x4 bv = *(const u32x4*)(hB + hr * 1152 + cbase);
                bf16x8 bfr = __builtin_bit_cast(bf16x8, bv);
#pragma unroll
                for (int m = 0; m < 4; ++m)
                    acc[m][n] = __builtin_amdgcn_mfma_f32_16x16x32_bf16(
                        __builtin_bit_cast(bf16x8, af[m]), bfr, acc[m][n], 0, 0, 0);
            }
            if (have) *(u32x4*)(AsWr + ((buf ^ 1) << 12)) = an;
            if (ks == 8) {                 // swap to ci-half 1
                __syncthreads();           // all waves done reading half-0 halo
                stage_halo(1);
            }
            __syncthreads();
            buf ^= 1;
        }
    }

    if (MODE == 0) {
        // ---- y = conv (bias cancels in train-mode BN; never added) ----
#pragma unroll
        for (int m = 0; m < 4; ++m) {
            int co = rowbase + m * 16 + q * 4;
#pragma unroll
            for (int n = 0; n < N_; ++n) {
                int pix = (py0 + wv * N_ + n) * 64 + px0 + cl;
                unsigned short* yp = ybf + (size_t)img * 256 * 4096 + pix;
#pragma unroll
                for (int j = 0; j < 4; ++j)
                    yp[(size_t)(co + j) * 4096] = f2bf(acc[m][n][j]);
            }
        }
        // ---- fused BN partial stats: per-block 64-channel (sum, sumsq) ----
        float* bnred = (float*)&As[0][0];    // 2 KB, k-loop reads already done
#pragma unroll
        for (int m = 0; m < 4; ++m) {
#pragma unroll
            for (int j = 0; j < 4; ++j) {
                float s = 0.f, qq = 0.f;
#pragma unroll
                for (int n = 0; n < N_; ++n) {
                    float v = acc[m][n][j];
                    s += v; qq += v * v;
                }
#pragma unroll
                for (int mask = 1; mask <= 8; mask <<= 1) {
                    s  += __shfl_xor(s,  mask, 64);
                    qq += __shfl_xor(qq, mask, 64);
                }
                if (cl == 0) {
                    int ci_ = (wv * 4 + q) * 16 + m * 4 + j;
                    bnred[ci_ * 2]     = s;
                    bnred[ci_ * 2 + 1] = qq;
                }
            }
        }
        __syncthreads();
        if (tid < 64) {
            int m_ = tid >> 4, qj = tid & 15;      // local ch = m*16 + q*4 + j
            float s = 0.f, qq = 0.f;
#pragma unroll
            for (int w = 0; w < 4; ++w) {
                int idx = ((w * 4 + (qj >> 2)) * 16 + m_ * 4 + (qj & 3)) * 2;
                s += bnred[idx]; qq += bnred[idx + 1];
            }
            prt[(size_t)(rowbase + tid) * 1024 + img * 16 + tile] = make_float2(s, qq);
        }
    } else {
        unsigned short* hbounce = &As[0][0];     // 4 KB reuse
        __syncthreads();
#pragma unroll
        for (int m = 0; m < 4; ++m) {
            int hc = grp * 16 + m * 4 + q;
            float sc[4], sh[4];
#pragma unroll
            for (int j = 0; j < 4; ++j) {
                sc[j] = ss[j * 64 + hc];
                sh[j] = ss[256 + j * 64 + hc];
            }
#pragma unroll
            for (int n = 0; n < N_; ++n) {
                int pix = (py0 + wv * N_ + n) * 64 + px0 + cl;
                float tmp[4];
#pragma unroll
                for (int j = 0; j < 4; ++j) {
                    float yv = bf2f(ybf[((size_t)((t * 4 + img) * 256 + j * 64 + hc)) * 4096 + pix]);
                    tmp[j] = acc[m][n][j] + sc[j] * yv + sh[j];
                }
                float iv = 1.f / (1.f + __expf(-tmp[0]));
                float fv = 1.f / (1.f + __expf(-tmp[1]));
                float ov = 1.f / (1.f + __expf(-tmp[2]));
                float e2 = __expf(2.f * tmp[3]);
                float gv = 1.f - 2.f / (e2 + 1.f);
                size_t cidx = ((size_t)img * 64 + hc) * 4096 + pix;
                float cnew = fv * cst[cidx] + iv * gv;
                cst[cidx] = cnew;
                float e2c = __expf(2.f * cnew);
                float hv  = ov * (1.f - 2.f / (e2c + 1.f));
                out[((size_t)(t * 4 + img) * 64 + hc) * 4096 + pix] = hv;
                hbounce[((wv * N_ + n) * 16 + cl) * 16 + m * 4 + q] = f2bf(hv);
            }
        }
        __syncthreads();
        // coalesced hT write-out: [img][pix][ci] slice grp*16..grp*16+15
        if (tid < TH * 16) {
            int pixg = (py0 + (tid >> 4)) * 64 + px0 + (tid & 15);
            u32x4* dst = (u32x4*)(hout + ((size_t)img * 4096 + pixg) * 64 + grp * 16);
            u32x4* s0  = (u32x4*)(hbounce + tid * 16);
            dst[0] = s0[0];
            dst[1] = s0[1];
        }
    }
}

// ---------------------------------------------------------------------------
// BN finalize: reduce 1024 per-block partials per channel -> scale/shift
// ---------------------------------------------------------------------------
__global__ __launch_bounds__(256) void k_bn_fin(
    const float2* __restrict__ prt, const float* __restrict__ bx,
    const float* __restrict__ gamma, const float* __restrict__ beta,
    float* __restrict__ ss) {
    int c = blockIdx.x;                       // 256 blocks
    const float2* p = prt + (size_t)c * 1024;
    float s = 0.f, sq = 0.f;
    for (int i = threadIdx.x; i < 1024; i += 256) {
        float2 v = p[i]; s += v.x; sq += v.y;
    }
    __shared__ float rs[256], rq[256];
    int tid = threadIdx.x;
    rs[tid] = s; rq[tid] = sq;
    __syncthreads();
    for (int off = 128; off > 0; off >>= 1) {
        if (tid < off) { rs[tid] += rs[tid + off]; rq[tid] += rq[tid + off]; }
        __syncthreads();
    }
    if (tid == 0) {
        float mean = rs[0] * (1.f / 262144.f);
        float var  = rq[0] * (1.f / 262144.f) - mean * mean;
        float sc   = gamma[c] * rsqrtf(var + 1e-5f);
        ss[c]       = sc;
        // conv bias bx cancels exactly in train-mode BN (mean contains it);
        // y was stored WITHOUT bias, so stats already match the bias-free conv:
        ss[256 + c] = beta[c] - mean * sc;
        (void)bx;
    }
}

// ---------------------------------------------------------------------------
extern "C" void kernel_launch(void* const* d_in, const int* in_sizes, int n_in,
                              void* d_out, int out_size, void* d_ws, size_t ws_size,
                              hipStream_t stream) {
    const float* x     = (const float*)d_in[0];
    const float* Wx    = (const float*)d_in[1];
    const float* bx    = (const float*)d_in[2];
    const float* gamma = (const float*)d_in[3];
    const float* beta  = (const float*)d_in[4];
    const float* Wh    = (const float*)d_in[5];
    float* out = (float*)d_out;

    char* ws = (char*)d_ws;
    unsigned short* y   = (unsigned short*)ws;                  // 134,217,728
    unsigned short* Axp = (unsigned short*)(ws + 134217728);    //     294,912
    unsigned short* Ahp = (unsigned short*)(ws + 134512640);    //     294,912
    float*          ss  = (float*)(ws + 134807552);             //       2,048
    float*          cs  = (float*)(ws + 134809600);             //   4,194,304
    // prt and hA share a 2 MB slot: prt is produced by k_conv<0> and fully
    // consumed by k_bn_fin before step t=1 first writes hA (t=0 writes hB).
    float2*         prt = (float2*)(ws + 139003904);            //   2,097,152
    unsigned short* hA  = (unsigned short*)(ws + 139003904);    //   (alias)
    unsigned short* hB  = (unsigned short*)(ws + 141101056);    //   2,097,152
    // total 143,198,208 B

    // xT scratch lives in d_out (dead once steps start overwriting it)
    unsigned short* xT = (unsigned short*)d_out;

    k_xT  <<<1024, 256, 0, stream>>>(x, xT);
    k_pack<<< 576, 256, 0, stream>>>(Wx, Axp, 0);
    k_pack<<< 576, 256, 0, stream>>>(Wh, Ahp, 1);
    hipMemsetAsync(cs, 0, 4194304, stream);

    k_conv<0><<<4096, 256, 0, stream>>>(xT, Axp, y, nullptr, nullptr, nullptr,
                                        nullptr, prt, 0, 0);
    k_bn_fin<<<256, 256, 0, stream>>>(prt, bx, gamma, beta, ss);

    unsigned short* hbuf[2] = {hA, hB};
    for (int t = 0; t < 16; ++t) {
        k_conv<1><<<512, 256, 0, stream>>>(hbuf[t & 1], Ahp, y, ss, cs,
                                           hbuf[(t + 1) & 1], out, nullptr,
                                           t, t == 0 ? 1 : 0);
    }
}